// Round 1
// baseline (141.653 us; speedup 1.0000x reference)
//
#include <hip/hip_runtime.h>

#define TILE 1024  // b-points staged per LDS round: 1024*3*4B = 12 KB

__global__ void cd_init_bits(unsigned int* __restrict__ p, int count) {
    int i = blockIdx.x * blockDim.x + threadIdx.x;
    if (i < count) p[i] = 0x7F800000u;  // +inf bits
}

// Each thread owns one query point of A (registers); scans a chunk of B staged
// through LDS. Min squared distance combined across b-chunks via atomicMin on
// float bits (valid: all values are non-negative floats).
__global__ __launch_bounds__(256) void cd_min_sqdist(
    const float* __restrict__ A, int n,
    const float* __restrict__ B, int m,
    int chunk, unsigned int* __restrict__ out_bits)
{
    __shared__ float sb[TILE * 3];
    const int tid = threadIdx.x;
    const int i = blockIdx.x * 256 + tid;
    const bool valid = (i < n);
    float ax = 0.f, ay = 0.f, az = 0.f;
    if (valid) {
        ax = A[3 * i + 0];
        ay = A[3 * i + 1];
        az = A[3 * i + 2];
    }
    float best = __builtin_inff();

    const int j0 = blockIdx.y * chunk;
    const int j1 = min(j0 + chunk, m);
    for (int jb = j0; jb < j1; jb += TILE) {
        const int cnt = min(TILE, j1 - jb);
        const int nf = cnt * 3;
        __syncthreads();  // protect previous tile from overwrite
        for (int t = tid; t < nf; t += 256)
            sb[t] = B[3 * jb + t];
        __syncthreads();

        const float4* sb4 = (const float4*)sb;
        int j = 0;
        for (; j + 4 <= cnt; j += 4) {
            const int q = 3 * (j >> 2);
            float4 p0 = sb4[q + 0];  // x0 y0 z0 x1
            float4 p1 = sb4[q + 1];  // y1 z1 x2 y2
            float4 p2 = sb4[q + 2];  // z2 x3 y3 z3
            float dx0 = ax - p0.x, dy0 = ay - p0.y, dz0 = az - p0.z;
            float d0 = fmaf(dx0, dx0, fmaf(dy0, dy0, dz0 * dz0));
            float dx1 = ax - p0.w, dy1 = ay - p1.x, dz1 = az - p1.y;
            float d1 = fmaf(dx1, dx1, fmaf(dy1, dy1, dz1 * dz1));
            float dx2 = ax - p1.z, dy2 = ay - p1.w, dz2 = az - p2.x;
            float d2 = fmaf(dx2, dx2, fmaf(dy2, dy2, dz2 * dz2));
            float dx3 = ax - p2.y, dy3 = ay - p2.z, dz3 = az - p2.w;
            float d3 = fmaf(dx3, dx3, fmaf(dy3, dy3, dz3 * dz3));
            best = fminf(best, fminf(fminf(d0, d1), fminf(d2, d3)));
        }
        for (; j < cnt; ++j) {
            float dx = ax - sb[3 * j], dy = ay - sb[3 * j + 1], dz = az - sb[3 * j + 2];
            best = fminf(best, fmaf(dx, dx, fmaf(dy, dy, dz * dz)));
        }
    }
    if (valid) atomicMin(&out_bits[i], __float_as_uint(best));
}

__global__ __launch_bounds__(1024) void cd_reduce(
    const unsigned int* __restrict__ bits, int count, float* __restrict__ out)
{
    __shared__ double sw[16];
    double s = 0.0;
    for (int i = threadIdx.x; i < count; i += 1024)
        s += (double)sqrtf(__uint_as_float(bits[i]));
    for (int off = 32; off > 0; off >>= 1)
        s += __shfl_down(s, off, 64);
    const int lane = threadIdx.x & 63, wid = threadIdx.x >> 6;
    if (lane == 0) sw[wid] = s;
    __syncthreads();
    if (threadIdx.x == 0) {
        double tot = 0.0;
        for (int w = 0; w < 16; ++w) tot += sw[w];
        out[0] = (float)(tot / (double)count);
    }
}

extern "C" void kernel_launch(void* const* d_in, const int* in_sizes, int n_in,
                              void* d_out, int out_size, void* d_ws, size_t ws_size,
                              hipStream_t stream) {
    const float* a = (const float*)d_in[0];
    const float* b = (const float*)d_in[1];
    const int n = in_sizes[0] / 3;
    const int m = in_sizes[1] / 3;
    unsigned int* bits = (unsigned int*)d_ws;  // n + m entries
    float* out = (float*)d_out;
    const int total = n + m;

    cd_init_bits<<<(total + 255) / 256, 256, 0, stream>>>(bits, total);

    const int SPLIT = 16;  // split the scanned set for occupancy: 64x16 = 1024 blocks/pass
    {
        const int chunk = (m + SPLIT - 1) / SPLIT;
        dim3 grid((n + 255) / 256, SPLIT);
        cd_min_sqdist<<<grid, 256, 0, stream>>>(a, n, b, m, chunk, bits);
    }
    {
        const int chunk = (n + SPLIT - 1) / SPLIT;
        dim3 grid((m + 255) / 256, SPLIT);
        cd_min_sqdist<<<grid, 256, 0, stream>>>(b, m, a, n, chunk, bits + n);
    }
    cd_reduce<<<1, 1024, 0, stream>>>(bits, total, out);
}

// Round 2
// 107.866 us; speedup vs baseline: 1.3132x; 1.3132x over previous
//
#include <hip/hip_runtime.h>

typedef unsigned int uint32;

// Prep: store each point as (-2x, -2y, -2z, x^2+y^2+z^2) so the scan body is a
// pure fma chain; also init the min-bits array to +inf.
__global__ __launch_bounds__(256) void cd_prep(
    const float* __restrict__ A, int n, const float* __restrict__ B, int m,
    float4* __restrict__ Ap, float4* __restrict__ Bp, uint32* __restrict__ bits)
{
    int i = blockIdx.x * 256 + threadIdx.x;
    int total = n + m;
    if (i < total) bits[i] = 0x7F800000u;  // +inf
    if (i < n) {
        float x = A[3 * i], y = A[3 * i + 1], z = A[3 * i + 2];
        Ap[i] = make_float4(-2.f * x, -2.f * y, -2.f * z, fmaf(x, x, fmaf(y, y, z * z)));
    } else if (i < total) {
        int j = i - n;
        float x = B[3 * j], y = B[3 * j + 1], z = B[3 * j + 2];
        Bp[j] = make_float4(-2.f * x, -2.f * y, -2.f * z, fmaf(x, x, fmaf(y, y, z * z)));
    }
}

__global__ void cd_init_bits(uint32* __restrict__ p, int count) {
    int i = blockIdx.x * blockDim.x + threadIdx.x;
    if (i < count) p[i] = 0x7F800000u;
}

// Each thread owns one query point (registers). The scanned set is read with a
// WAVE-UNIFORM index -> scalar/broadcast loads, no LDS, no per-lane VMEM.
// Tracks min_j(b^2 - 2 a.b); a^2 added once at the end.
__global__ __launch_bounds__(256) void cd_pass(
    const float* __restrict__ Qraw, int nq,
    const float4* __restrict__ Sp, int ns,
    int chunk, uint32* __restrict__ outbits)
{
    const int i = blockIdx.x * 256 + threadIdx.x;
    float ax = 0.f, ay = 0.f, az = 0.f;
    if (i < nq) { ax = Qraw[3 * i]; ay = Qraw[3 * i + 1]; az = Qraw[3 * i + 2]; }
    const float a2 = fmaf(ax, ax, fmaf(ay, ay, az * az));

    const int j0 = blockIdx.y * chunk;
    const int j1 = min(j0 + chunk, ns);
    float m0 = __builtin_inff(), m1 = __builtin_inff();
    float m2 = __builtin_inff(), m3 = __builtin_inff();

    int j = j0;
    for (; j + 8 <= j1; j += 8) {
        float4 b0 = Sp[j + 0], b1 = Sp[j + 1], b2 = Sp[j + 2], b3 = Sp[j + 3];
        float4 b4 = Sp[j + 4], b5 = Sp[j + 5], b6 = Sp[j + 6], b7 = Sp[j + 7];
        float t0 = fmaf(b0.x, ax, fmaf(b0.y, ay, fmaf(b0.z, az, b0.w)));
        float t1 = fmaf(b1.x, ax, fmaf(b1.y, ay, fmaf(b1.z, az, b1.w)));
        float t2 = fmaf(b2.x, ax, fmaf(b2.y, ay, fmaf(b2.z, az, b2.w)));
        float t3 = fmaf(b3.x, ax, fmaf(b3.y, ay, fmaf(b3.z, az, b3.w)));
        float t4 = fmaf(b4.x, ax, fmaf(b4.y, ay, fmaf(b4.z, az, b4.w)));
        float t5 = fmaf(b5.x, ax, fmaf(b5.y, ay, fmaf(b5.z, az, b5.w)));
        float t6 = fmaf(b6.x, ax, fmaf(b6.y, ay, fmaf(b6.z, az, b6.w)));
        float t7 = fmaf(b7.x, ax, fmaf(b7.y, ay, fmaf(b7.z, az, b7.w)));
        m0 = fminf(fminf(m0, t0), t1);  // fuses to v_min3_f32
        m1 = fminf(fminf(m1, t2), t3);
        m2 = fminf(fminf(m2, t4), t5);
        m3 = fminf(fminf(m3, t6), t7);
    }
    for (; j < j1; ++j) {
        float4 b = Sp[j];
        m0 = fminf(m0, fmaf(b.x, ax, fmaf(b.y, ay, fmaf(b.z, az, b.w))));
    }
    if (i < nq) {
        float sq = fmaxf(a2 + fminf(fminf(m0, m1), fminf(m2, m3)), 0.f);
        atomicMin(&outbits[i], __float_as_uint(sq));
    }
}

// Fallback (tiny ws): scan raw xyz and compute b^2 on the fly. Same math.
__global__ __launch_bounds__(256) void cd_pass_raw(
    const float* __restrict__ Qraw, int nq,
    const float* __restrict__ Sraw, int ns,
    int chunk, uint32* __restrict__ outbits)
{
    const int i = blockIdx.x * 256 + threadIdx.x;
    float ax = 0.f, ay = 0.f, az = 0.f;
    if (i < nq) { ax = Qraw[3 * i]; ay = Qraw[3 * i + 1]; az = Qraw[3 * i + 2]; }
    const float nax = -2.f * ax, nay = -2.f * ay, naz = -2.f * az;
    const float a2 = fmaf(ax, ax, fmaf(ay, ay, az * az));
    const int j0 = blockIdx.y * chunk;
    const int j1 = min(j0 + chunk, ns);
    float m0 = __builtin_inff();
    for (int j = j0; j < j1; ++j) {
        float sx = Sraw[3 * j], sy = Sraw[3 * j + 1], sz = Sraw[3 * j + 2];
        float s2 = fmaf(sx, sx, fmaf(sy, sy, sz * sz));
        m0 = fminf(m0, fmaf(sx, nax, fmaf(sy, nay, fmaf(sz, naz, s2))));
    }
    if (i < nq) {
        float sq = fmaxf(a2 + m0, 0.f);
        atomicMin(&outbits[i], __float_as_uint(sq));
    }
}

__global__ __launch_bounds__(1024) void cd_reduce(
    const uint32* __restrict__ bits, int count, float* __restrict__ out)
{
    __shared__ double sw[16];
    double s = 0.0;
    for (int i = threadIdx.x; i < count; i += 1024)
        s += (double)sqrtf(__uint_as_float(bits[i]));
    for (int off = 32; off > 0; off >>= 1)
        s += __shfl_down(s, off, 64);
    const int lane = threadIdx.x & 63, wid = threadIdx.x >> 6;
    if (lane == 0) sw[wid] = s;
    __syncthreads();
    if (threadIdx.x == 0) {
        double tot = 0.0;
        for (int w = 0; w < 16; ++w) tot += sw[w];
        out[0] = (float)(tot / (double)count);
    }
}

extern "C" void kernel_launch(void* const* d_in, const int* in_sizes, int n_in,
                              void* d_out, int out_size, void* d_ws, size_t ws_size,
                              hipStream_t stream) {
    const float* a = (const float*)d_in[0];
    const float* b = (const float*)d_in[1];
    const int n = in_sizes[0] / 3;
    const int m = in_sizes[1] / 3;
    const int total = n + m;
    float* out = (float*)d_out;

    uint32* bits = (uint32*)d_ws;
    size_t bitsBytes = ((size_t)total * 4 + 255) & ~(size_t)255;
    float4* Ap = (float4*)((char*)d_ws + bitsBytes);
    float4* Bp = Ap + n;
    const size_t needed = bitsBytes + (size_t)total * 16;

    const int SPLIT = 32;  // 64x32 = 2048 blocks/pass -> 8 blocks/CU, full occupancy

    if (ws_size >= needed) {
        cd_prep<<<(total + 255) / 256, 256, 0, stream>>>(a, n, b, m, Ap, Bp, bits);
        {
            const int chunk = (m + SPLIT - 1) / SPLIT;
            dim3 grid((n + 255) / 256, SPLIT);
            cd_pass<<<grid, 256, 0, stream>>>(a, n, Bp, m, chunk, bits);
        }
        {
            const int chunk = (n + SPLIT - 1) / SPLIT;
            dim3 grid((m + 255) / 256, SPLIT);
            cd_pass<<<grid, 256, 0, stream>>>(b, m, Ap, n, chunk, bits + n);
        }
    } else {
        cd_init_bits<<<(total + 255) / 256, 256, 0, stream>>>(bits, total);
        {
            const int chunk = (m + SPLIT - 1) / SPLIT;
            dim3 grid((n + 255) / 256, SPLIT);
            cd_pass_raw<<<grid, 256, 0, stream>>>(a, n, b, m, chunk, bits);
        }
        {
            const int chunk = (n + SPLIT - 1) / SPLIT;
            dim3 grid((m + 255) / 256, SPLIT);
            cd_pass_raw<<<grid, 256, 0, stream>>>(b, m, a, n, chunk, bits + n);
        }
    }
    cd_reduce<<<1, 1024, 0, stream>>>(bits, total, out);
}

// Round 3
// 86.531 us; speedup vs baseline: 1.6370x; 1.2466x over previous
//
#include <hip/hip_runtime.h>

typedef unsigned int uint32;

#define QT 8  // queries per thread

// Prep: store each point as (-2x, -2y, -2z, x^2+y^2+z^2); init min-bits to +inf.
__global__ __launch_bounds__(256) void cd_prep(
    const float* __restrict__ A, int n, const float* __restrict__ B, int m,
    float4* __restrict__ Ap, float4* __restrict__ Bp, uint32* __restrict__ bits)
{
    int i = blockIdx.x * 256 + threadIdx.x;
    int total = n + m;
    if (i < total) bits[i] = 0x7F800000u;  // +inf
    if (i < n) {
        float x = A[3 * i], y = A[3 * i + 1], z = A[3 * i + 2];
        Ap[i] = make_float4(-2.f * x, -2.f * y, -2.f * z, fmaf(x, x, fmaf(y, y, z * z)));
    } else if (i < total) {
        int j = i - n;
        float x = B[3 * j], y = B[3 * j + 1], z = B[3 * j + 2];
        Bp[j] = make_float4(-2.f * x, -2.f * y, -2.f * z, fmaf(x, x, fmaf(y, y, z * z)));
    }
}

__global__ void cd_init_bits(uint32* __restrict__ p, int count) {
    int i = blockIdx.x * blockDim.x + threadIdx.x;
    if (i < count) p[i] = 0x7F800000u;
}

// 8 queries per thread in registers; scanned set read with a wave-uniform index
// (scalar loads into SGPRs, reused by all 8 fma chains). Tracks
// min_j(b^2 - 2 a.b); a^2 added at the tail (keeps atomic values >= 0).
__global__ __launch_bounds__(256) void cd_pass_q8(
    const float* __restrict__ Qraw, int nq,
    const float4* __restrict__ Sp, int ns,
    int chunk, uint32* __restrict__ outbits)
{
    const int nthreads = gridDim.x * 256;
    const int t = blockIdx.x * 256 + threadIdx.x;

    float qx[QT], qy[QT], qz[QT], mn[QT];
#pragma unroll
    for (int k = 0; k < QT; ++k) {
        const int i = t + k * nthreads;
        const bool v = (i < nq);
        qx[k] = v ? Qraw[3 * i + 0] : 0.f;
        qy[k] = v ? Qraw[3 * i + 1] : 0.f;
        qz[k] = v ? Qraw[3 * i + 2] : 0.f;
        mn[k] = __builtin_inff();
    }

    const int j0 = blockIdx.y * chunk;
    const int j1 = min(j0 + chunk, ns);
    int j = j0;
    for (; j + 4 <= j1; j += 4) {
        const float4 b0 = Sp[j + 0];
        const float4 b1 = Sp[j + 1];
        const float4 b2 = Sp[j + 2];
        const float4 b3 = Sp[j + 3];
#pragma unroll
        for (int k = 0; k < QT; ++k) {
            float t0 = fmaf(b0.x, qx[k], fmaf(b0.y, qy[k], fmaf(b0.z, qz[k], b0.w)));
            float t1 = fmaf(b1.x, qx[k], fmaf(b1.y, qy[k], fmaf(b1.z, qz[k], b1.w)));
            mn[k] = fminf(fminf(mn[k], t0), t1);
            float t2 = fmaf(b2.x, qx[k], fmaf(b2.y, qy[k], fmaf(b2.z, qz[k], b2.w)));
            float t3 = fmaf(b3.x, qx[k], fmaf(b3.y, qy[k], fmaf(b3.z, qz[k], b3.w)));
            mn[k] = fminf(fminf(mn[k], t2), t3);
        }
    }
    for (; j < j1; ++j) {
        const float4 b = Sp[j];
#pragma unroll
        for (int k = 0; k < QT; ++k)
            mn[k] = fminf(mn[k], fmaf(b.x, qx[k], fmaf(b.y, qy[k], fmaf(b.z, qz[k], b.w))));
    }

#pragma unroll
    for (int k = 0; k < QT; ++k) {
        const int i = t + k * nthreads;
        if (i < nq) {
            const float a2 = fmaf(qx[k], qx[k], fmaf(qy[k], qy[k], qz[k] * qz[k]));
            const float sq = fmaxf(a2 + mn[k], 0.f);
            atomicMin(&outbits[i], __float_as_uint(sq));
        }
    }
}

// Fallback (tiny ws): raw scan, computes b^2 on the fly.
__global__ __launch_bounds__(256) void cd_pass_raw(
    const float* __restrict__ Qraw, int nq,
    const float* __restrict__ Sraw, int ns,
    int chunk, uint32* __restrict__ outbits)
{
    const int i = blockIdx.x * 256 + threadIdx.x;
    float ax = 0.f, ay = 0.f, az = 0.f;
    if (i < nq) { ax = Qraw[3 * i]; ay = Qraw[3 * i + 1]; az = Qraw[3 * i + 2]; }
    const float nax = -2.f * ax, nay = -2.f * ay, naz = -2.f * az;
    const float a2 = fmaf(ax, ax, fmaf(ay, ay, az * az));
    const int j0 = blockIdx.y * chunk;
    const int j1 = min(j0 + chunk, ns);
    float m0 = __builtin_inff();
    for (int j = j0; j < j1; ++j) {
        float sx = Sraw[3 * j], sy = Sraw[3 * j + 1], sz = Sraw[3 * j + 2];
        float s2 = fmaf(sx, sx, fmaf(sy, sy, sz * sz));
        m0 = fminf(m0, fmaf(sx, nax, fmaf(sy, nay, fmaf(sz, naz, s2))));
    }
    if (i < nq) {
        float sq = fmaxf(a2 + m0, 0.f);
        atomicMin(&outbits[i], __float_as_uint(sq));
    }
}

__global__ __launch_bounds__(1024) void cd_reduce(
    const uint32* __restrict__ bits, int count, float* __restrict__ out)
{
    __shared__ double sw[16];
    double s = 0.0;
    for (int i = threadIdx.x; i < count; i += 1024)
        s += (double)sqrtf(__uint_as_float(bits[i]));
    for (int off = 32; off > 0; off >>= 1)
        s += __shfl_down(s, off, 64);
    const int lane = threadIdx.x & 63, wid = threadIdx.x >> 6;
    if (lane == 0) sw[wid] = s;
    __syncthreads();
    if (threadIdx.x == 0) {
        double tot = 0.0;
        for (int w = 0; w < 16; ++w) tot += sw[w];
        out[0] = (float)(tot / (double)count);
    }
}

extern "C" void kernel_launch(void* const* d_in, const int* in_sizes, int n_in,
                              void* d_out, int out_size, void* d_ws, size_t ws_size,
                              hipStream_t stream) {
    const float* a = (const float*)d_in[0];
    const float* b = (const float*)d_in[1];
    const int n = in_sizes[0] / 3;
    const int m = in_sizes[1] / 3;
    const int total = n + m;
    float* out = (float*)d_out;

    uint32* bits = (uint32*)d_ws;
    size_t bitsBytes = ((size_t)total * 4 + 255) & ~(size_t)255;
    float4* Ap = (float4*)((char*)d_ws + bitsBytes);
    float4* Bp = Ap + n;
    const size_t needed = bitsBytes + (size_t)total * 16;

    if (ws_size >= needed) {
        cd_prep<<<(total + 255) / 256, 256, 0, stream>>>(a, n, b, m, Ap, Bp, bits);
        {
            // queries = a (scan Bp)
            const int bx = (n + QT * 256 - 1) / (QT * 256);
            const int SPLIT = 256;
            const int chunk = (m + SPLIT - 1) / SPLIT;
            dim3 grid(bx, SPLIT);
            cd_pass_q8<<<grid, 256, 0, stream>>>(a, n, Bp, m, chunk, bits);
        }
        {
            // queries = b (scan Ap)
            const int bx = (m + QT * 256 - 1) / (QT * 256);
            const int SPLIT = 256;
            const int chunk = (n + SPLIT - 1) / SPLIT;
            dim3 grid(bx, SPLIT);
            cd_pass_q8<<<grid, 256, 0, stream>>>(b, m, Ap, n, chunk, bits + n);
        }
    } else {
        cd_init_bits<<<(total + 255) / 256, 256, 0, stream>>>(bits, total);
        const int SPLIT = 32;
        {
            const int chunk = (m + SPLIT - 1) / SPLIT;
            dim3 grid((n + 255) / 256, SPLIT);
            cd_pass_raw<<<grid, 256, 0, stream>>>(a, n, b, m, chunk, bits);
        }
        {
            const int chunk = (n + SPLIT - 1) / SPLIT;
            dim3 grid((m + 255) / 256, SPLIT);
            cd_pass_raw<<<grid, 256, 0, stream>>>(b, m, a, n, chunk, bits + n);
        }
    }
    cd_reduce<<<1, 1024, 0, stream>>>(bits, total, out);
}

// Round 4
// 72.667 us; speedup vs baseline: 1.9494x; 1.1908x over previous
//
#include <hip/hip_runtime.h>

typedef unsigned int uint32;

#define QT 8        // queries per thread
#define THREADS 256

// Pack each point as (-2x, -2y, -2z, x^2+y^2+z^2).
__global__ __launch_bounds__(THREADS) void cd_prep(
    const float* __restrict__ A, int n, const float* __restrict__ B, int m,
    float4* __restrict__ Ap, float4* __restrict__ Bp)
{
    int i = blockIdx.x * THREADS + threadIdx.x;
    if (i < n) {
        float x = A[3 * i], y = A[3 * i + 1], z = A[3 * i + 2];
        Ap[i] = make_float4(-2.f * x, -2.f * y, -2.f * z, fmaf(x, x, fmaf(y, y, z * z)));
    }
    if (i < m) {
        float x = B[3 * i], y = B[3 * i + 1], z = B[3 * i + 2];
        Bp[i] = make_float4(-2.f * x, -2.f * y, -2.f * z, fmaf(x, x, fmaf(y, y, z * z)));
    }
}

// Both chamfer directions in one launch (blockIdx.z). 8 queries/thread in
// registers; scanned set read with wave-uniform index (SGPR loads, shared by
// all 8 fma chains), software-pipelined. Per (y-chunk) partial min of
// (a^2 + b^2 - 2 a.b) is clamped at 0 and stored to P[y][i] — no atomics.
__global__ __launch_bounds__(THREADS) void cd_pass_fused(
    const float4* __restrict__ Ap, int n,
    const float4* __restrict__ Bp, int m,
    int split, float* __restrict__ P0, float* __restrict__ P1)
{
    const float4* Q; const float4* S; float* P; int nq, ns;
    if (blockIdx.z == 0) { Q = Ap; nq = n; S = Bp; ns = m; P = P0; }
    else                 { Q = Bp; nq = m; S = Ap; ns = n; P = P1; }

    const int nth = gridDim.x * THREADS;
    const int t = blockIdx.x * THREADS + threadIdx.x;

    float qx[QT], qy[QT], qz[QT], a2[QT], mn[QT];
#pragma unroll
    for (int k = 0; k < QT; ++k) {
        const int i = t + k * nth;
        float4 q = (i < nq) ? Q[i] : make_float4(0.f, 0.f, 0.f, 0.f);
        qx[k] = -0.5f * q.x;  // back to plain (x,y,z)
        qy[k] = -0.5f * q.y;
        qz[k] = -0.5f * q.z;
        a2[k] = q.w;
        mn[k] = __builtin_inff();
    }

    const int chunk = (ns + split - 1) / split;
    const int j0 = blockIdx.y * chunk;
    const int j1 = min(j0 + chunk, ns);

    auto step4 = [&](const float4& b0, const float4& b1,
                     const float4& b2, const float4& b3) {
#pragma unroll
        for (int k = 0; k < QT; ++k) {
            float t0 = fmaf(b0.x, qx[k], fmaf(b0.y, qy[k], fmaf(b0.z, qz[k], b0.w)));
            float t1 = fmaf(b1.x, qx[k], fmaf(b1.y, qy[k], fmaf(b1.z, qz[k], b1.w)));
            mn[k] = fminf(fminf(mn[k], t0), t1);   // v_min3_f32
            float t2 = fmaf(b2.x, qx[k], fmaf(b2.y, qy[k], fmaf(b2.z, qz[k], b2.w)));
            float t3 = fmaf(b3.x, qx[k], fmaf(b3.y, qy[k], fmaf(b3.z, qz[k], b3.w)));
            mn[k] = fminf(fminf(mn[k], t2), t3);
        }
    };

    int j = j0;
    float4 c0, c1, c2, c3;
    const bool have = (j + 4 <= j1);
    if (have) { c0 = S[j]; c1 = S[j + 1]; c2 = S[j + 2]; c3 = S[j + 3]; }
    for (; j + 8 <= j1; j += 4) {
        float4 n0 = S[j + 4], n1 = S[j + 5], n2 = S[j + 6], n3 = S[j + 7];
        step4(c0, c1, c2, c3);
        c0 = n0; c1 = n1; c2 = n2; c3 = n3;
    }
    if (have) { step4(c0, c1, c2, c3); j += 4; }
    for (; j < j1; ++j) {
        const float4 b = S[j];
#pragma unroll
        for (int k = 0; k < QT; ++k)
            mn[k] = fminf(mn[k], fmaf(b.x, qx[k], fmaf(b.y, qy[k], fmaf(b.z, qz[k], b.w))));
    }

    float* row = P + (size_t)blockIdx.y * nq;
#pragma unroll
    for (int k = 0; k < QT; ++k) {
        const int i = t + k * nth;
        if (i < nq) row[i] = fmaxf(a2[k] + mn[k], 0.f);
    }
}

// Stage 1: per query, min over the split partials, sqrt, block-sum (double).
__global__ __launch_bounds__(THREADS) void cd_reduce1(
    const float* __restrict__ P0, int n,
    const float* __restrict__ P1, int m,
    int split, double* __restrict__ partials)
{
    const int q = blockIdx.x * THREADS + threadIdx.x;
    const int total = n + m;
    double s = 0.0;
    if (q < total) {
        const float* P; int nq, i;
        if (q < n) { P = P0; nq = n; i = q; }
        else       { P = P1; nq = m; i = q - n; }
        float v = P[i];
#pragma unroll 4
        for (int r = 1; r < split; ++r) v = fminf(v, P[(size_t)r * nq + i]);
        s = (double)sqrtf(v);
    }
#pragma unroll
    for (int off = 32; off > 0; off >>= 1) s += __shfl_down(s, off, 64);
    __shared__ double sw[4];
    const int lane = threadIdx.x & 63, wid = threadIdx.x >> 6;
    if (lane == 0) sw[wid] = s;
    __syncthreads();
    if (threadIdx.x == 0) partials[blockIdx.x] = sw[0] + sw[1] + sw[2] + sw[3];
}

// Stage 2: deterministic fixed-order sum of block partials -> mean.
__global__ __launch_bounds__(THREADS) void cd_reduce2(
    const double* __restrict__ partials, int nb, int total, float* __restrict__ out)
{
    double s = 0.0;
    for (int i = threadIdx.x; i < nb; i += THREADS) s += partials[i];
#pragma unroll
    for (int off = 32; off > 0; off >>= 1) s += __shfl_down(s, off, 64);
    __shared__ double sw[4];
    const int lane = threadIdx.x & 63, wid = threadIdx.x >> 6;
    if (lane == 0) sw[wid] = s;
    __syncthreads();
    if (threadIdx.x == 0)
        out[0] = (float)((sw[0] + sw[1] + sw[2] + sw[3]) / (double)total);
}

extern "C" void kernel_launch(void* const* d_in, const int* in_sizes, int n_in,
                              void* d_out, int out_size, void* d_ws, size_t ws_size,
                              hipStream_t stream) {
    const float* a = (const float*)d_in[0];
    const float* b = (const float*)d_in[1];
    const int n = in_sizes[0] / 3;
    const int m = in_sizes[1] / 3;
    const int total = n + m;
    float* out = (float*)d_out;

    // ws layout: Ap[n] f4 | Bp[m] f4 | P0[split*n] f | P1[split*m] f | partials
    char* wp = (char*)d_ws;
    float4* Ap = (float4*)wp;                     wp += (size_t)n * 16;
    float4* Bp = (float4*)wp;                     wp += (size_t)m * 16;
    const size_t head = (size_t)total * 16;
    const int nb1 = (total + THREADS - 1) / THREADS;

    int split = 128;
    while (split > 1 &&
           head + (size_t)split * total * 4 + 256 + (size_t)nb1 * 8 > ws_size)
        split >>= 1;

    float* P0 = (float*)wp;                       wp += (size_t)split * n * 4;
    float* P1 = (float*)wp;                       wp += (size_t)split * m * 4;
    wp = (char*)(((size_t)wp + 255) & ~(size_t)255);
    double* partials = (double*)wp;

    const int mx = max(n, m);
    cd_prep<<<(mx + THREADS - 1) / THREADS, THREADS, 0, stream>>>(a, n, b, m, Ap, Bp);

    const int bx = (mx + QT * THREADS - 1) / (QT * THREADS);
    dim3 grid(bx, split, 2);
    cd_pass_fused<<<grid, THREADS, 0, stream>>>(Ap, n, Bp, m, split, P0, P1);

    cd_reduce1<<<nb1, THREADS, 0, stream>>>(P0, n, P1, m, split, partials);
    cd_reduce2<<<1, THREADS, 0, stream>>>(partials, nb1, total, out);
}

// Round 5
// 57.593 us; speedup vs baseline: 2.4596x; 1.2617x over previous
//
#include <hip/hip_runtime.h>

#define QT 8          // queries per thread
#define THREADS 256
#define MAXCHUNK 512  // points staged per LDS round (512 * 16B = 8 KB)

// Pack each point as (x, y, z, x^2+y^2+z^2).
__global__ __launch_bounds__(THREADS) void cd_prep(
    const float* __restrict__ A, int n, const float* __restrict__ B, int m,
    float4* __restrict__ Ap, float4* __restrict__ Bp)
{
    int i = blockIdx.x * THREADS + threadIdx.x;
    if (i < n) {
        float x = A[3 * i], y = A[3 * i + 1], z = A[3 * i + 2];
        Ap[i] = make_float4(x, y, z, fmaf(x, x, fmaf(y, y, z * z)));
    }
    if (i < m) {
        float x = B[3 * i], y = B[3 * i + 1], z = B[3 * i + 2];
        Bp[i] = make_float4(x, y, z, fmaf(x, x, fmaf(y, y, z * z)));
    }
}

// Both chamfer directions in one launch (blockIdx.z). 8 queries/thread in
// registers (qx = -2*x etc. so the body is a pure fma chain). Scanned chunk is
// staged in LDS and read with wave-uniform ds_read_b128 broadcasts — no scalar
// memory in the hot loop (SQC bandwidth was the round-4 wall), in-order
// lgkmcnt, all-VGPR operands. Tracks min_j(b^2 - 2 a.b); per-chunk partial of
// a^2 + min is clamped at 0 and stored to P[y][i] — no atomics, deterministic.
__global__ __launch_bounds__(THREADS) void cd_pass_fused(
    const float4* __restrict__ Ap, int n,
    const float4* __restrict__ Bp, int m,
    int split, float* __restrict__ P0, float* __restrict__ P1)
{
    __shared__ float4 sb[MAXCHUNK];

    const float4* Q; const float4* S; float* P; int nq, ns;
    if (blockIdx.z == 0) { Q = Ap; nq = n; S = Bp; ns = m; P = P0; }
    else                 { Q = Bp; nq = m; S = Ap; ns = n; P = P1; }

    const int nth = gridDim.x * THREADS;
    const int t = blockIdx.x * THREADS + threadIdx.x;

    float qx[QT], qy[QT], qz[QT], a2[QT], mn[QT];
#pragma unroll
    for (int k = 0; k < QT; ++k) {
        const int i = t + k * nth;
        float4 q = (i < nq) ? Q[i] : make_float4(0.f, 0.f, 0.f, 0.f);
        qx[k] = -2.f * q.x;
        qy[k] = -2.f * q.y;
        qz[k] = -2.f * q.z;
        a2[k] = q.w;
        mn[k] = __builtin_inff();
    }

    const int chunk = (ns + split - 1) / split;
    const int j0 = blockIdx.y * chunk;
    const int j1 = min(j0 + chunk, ns);

    for (int base = j0; base < j1; base += MAXCHUNK) {
        const int cnt = min(MAXCHUNK, j1 - base);
        __syncthreads();
        for (int u = threadIdx.x; u < cnt; u += THREADS)
            sb[u] = S[base + u];
        __syncthreads();

        int j = 0;
        for (; j + 8 <= cnt; j += 8) {
            float4 b0 = sb[j + 0], b1 = sb[j + 1], b2 = sb[j + 2], b3 = sb[j + 3];
            float4 b4 = sb[j + 4], b5 = sb[j + 5], b6 = sb[j + 6], b7 = sb[j + 7];
#pragma unroll
            for (int k = 0; k < QT; ++k) {
                float t0 = fmaf(b0.x, qx[k], fmaf(b0.y, qy[k], fmaf(b0.z, qz[k], b0.w)));
                float t1 = fmaf(b1.x, qx[k], fmaf(b1.y, qy[k], fmaf(b1.z, qz[k], b1.w)));
                mn[k] = fminf(fminf(mn[k], t0), t1);   // v_min3_f32
                float t2 = fmaf(b2.x, qx[k], fmaf(b2.y, qy[k], fmaf(b2.z, qz[k], b2.w)));
                float t3 = fmaf(b3.x, qx[k], fmaf(b3.y, qy[k], fmaf(b3.z, qz[k], b3.w)));
                mn[k] = fminf(fminf(mn[k], t2), t3);
                float t4 = fmaf(b4.x, qx[k], fmaf(b4.y, qy[k], fmaf(b4.z, qz[k], b4.w)));
                float t5 = fmaf(b5.x, qx[k], fmaf(b5.y, qy[k], fmaf(b5.z, qz[k], b5.w)));
                mn[k] = fminf(fminf(mn[k], t4), t5);
                float t6 = fmaf(b6.x, qx[k], fmaf(b6.y, qy[k], fmaf(b6.z, qz[k], b6.w)));
                float t7 = fmaf(b7.x, qx[k], fmaf(b7.y, qy[k], fmaf(b7.z, qz[k], b7.w)));
                mn[k] = fminf(fminf(mn[k], t6), t7);
            }
        }
        for (; j < cnt; ++j) {
            const float4 b = sb[j];
#pragma unroll
            for (int k = 0; k < QT; ++k)
                mn[k] = fminf(mn[k], fmaf(b.x, qx[k], fmaf(b.y, qy[k], fmaf(b.z, qz[k], b.w))));
        }
    }

    float* row = P + (size_t)blockIdx.y * nq;
#pragma unroll
    for (int k = 0; k < QT; ++k) {
        const int i = t + k * nth;
        if (i < nq) row[i] = fmaxf(a2[k] + mn[k], 0.f);
    }
}

// Stage 1: per query, min over the split partials, sqrt, block-sum (double).
__global__ __launch_bounds__(THREADS) void cd_reduce1(
    const float* __restrict__ P0, int n,
    const float* __restrict__ P1, int m,
    int split, double* __restrict__ partials)
{
    const int q = blockIdx.x * THREADS + threadIdx.x;
    const int total = n + m;
    double s = 0.0;
    if (q < total) {
        const float* P; int nq, i;
        if (q < n) { P = P0; nq = n; i = q; }
        else       { P = P1; nq = m; i = q - n; }
        float v = P[i];
#pragma unroll 4
        for (int r = 1; r < split; ++r) v = fminf(v, P[(size_t)r * nq + i]);
        s = (double)sqrtf(v);
    }
#pragma unroll
    for (int off = 32; off > 0; off >>= 1) s += __shfl_down(s, off, 64);
    __shared__ double sw[4];
    const int lane = threadIdx.x & 63, wid = threadIdx.x >> 6;
    if (lane == 0) sw[wid] = s;
    __syncthreads();
    if (threadIdx.x == 0) partials[blockIdx.x] = sw[0] + sw[1] + sw[2] + sw[3];
}

// Stage 2: deterministic fixed-order sum of block partials -> mean.
__global__ __launch_bounds__(THREADS) void cd_reduce2(
    const double* __restrict__ partials, int nb, int total, float* __restrict__ out)
{
    double s = 0.0;
    for (int i = threadIdx.x; i < nb; i += THREADS) s += partials[i];
#pragma unroll
    for (int off = 32; off > 0; off >>= 1) s += __shfl_down(s, off, 64);
    __shared__ double sw[4];
    const int lane = threadIdx.x & 63, wid = threadIdx.x >> 6;
    if (lane == 0) sw[wid] = s;
    __syncthreads();
    if (threadIdx.x == 0)
        out[0] = (float)((sw[0] + sw[1] + sw[2] + sw[3]) / (double)total);
}

extern "C" void kernel_launch(void* const* d_in, const int* in_sizes, int n_in,
                              void* d_out, int out_size, void* d_ws, size_t ws_size,
                              hipStream_t stream) {
    const float* a = (const float*)d_in[0];
    const float* b = (const float*)d_in[1];
    const int n = in_sizes[0] / 3;
    const int m = in_sizes[1] / 3;
    const int total = n + m;
    float* out = (float*)d_out;

    // ws layout: Ap[n] f4 | Bp[m] f4 | P0[split*n] f | P1[split*m] f | partials
    char* wp = (char*)d_ws;
    float4* Ap = (float4*)wp;                     wp += (size_t)n * 16;
    float4* Bp = (float4*)wp;                     wp += (size_t)m * 16;
    const size_t head = (size_t)total * 16;
    const int nb1 = (total + THREADS - 1) / THREADS;

    int split = 128;
    while (split > 1 &&
           head + (size_t)split * total * 4 + 256 + (size_t)nb1 * 8 > ws_size)
        split >>= 1;

    float* P0 = (float*)wp;                       wp += (size_t)split * n * 4;
    float* P1 = (float*)wp;                       wp += (size_t)split * m * 4;
    wp = (char*)(((size_t)wp + 255) & ~(size_t)255);
    double* partials = (double*)wp;

    const int mx = max(n, m);
    cd_prep<<<(mx + THREADS - 1) / THREADS, THREADS, 0, stream>>>(a, n, b, m, Ap, Bp);

    const int bx = (mx + QT * THREADS - 1) / (QT * THREADS);
    dim3 grid(bx, split, 2);
    cd_pass_fused<<<grid, THREADS, 0, stream>>>(Ap, n, Bp, m, split, P0, P1);

    cd_reduce1<<<nb1, THREADS, 0, stream>>>(P0, n, P1, m, split, partials);
    cd_reduce2<<<1, THREADS, 0, stream>>>(partials, nb1, total, out);
}